// Round 1
// baseline (1726.897 us; speedup 1.0000x reference)
//
#include <hip/hip_runtime.h>
#include <hip/hip_bf16.h>
#include <stdint.h>

#define NB 512
#define NW 40
#define NE 512
#define NH 512
#define NV 12000
#define G4 2048

typedef unsigned short u16;
typedef __attribute__((ext_vector_type(8))) short short8;
typedef __attribute__((ext_vector_type(4))) float f32x4;

__device__ __forceinline__ unsigned short f2bf(float f) {
  unsigned int u = __float_as_uint(f);
  u += 0x7FFF + ((u >> 16) & 1);
  return (unsigned short)(u >> 16);
}
__device__ __forceinline__ float bf2f(unsigned short b) {
  return __uint_as_float(((unsigned int)b) << 16);
}
// flag==1: float inputs are actually bf16 on device; flag==0: fp32
__device__ __forceinline__ float loadIn(const void* p, long i, int bf) {
  return bf ? bf2f(((const u16*)p)[i]) : ((const float*)p)[i];
}

// ---------------- dtype detector ----------------
// fp32 little-endian: even u16s are low mantissa bits (random exponent when
// viewed as bf16). bf16: every u16 is a real small value (exp in [100,126]).
__global__ void detect_kernel(const u16* p, int* flag) {
  __shared__ int cnt;
  int i = threadIdx.x;
  if (i == 0) cnt = 0;
  __syncthreads();
  unsigned short u = p[2 * (i * 1001)];
  int e = (u >> 7) & 0xFF;
  if (e >= 100 && e <= 126) atomicAdd(&cnt, 1);
  __syncthreads();
  if (i == 0) *flag = (cnt >= 32) ? 1 : 0;
}

// ---------------- tableT = bf16(tanh(lookup_W^T)), (V, E) ----------------
__global__ void table_kernel(const void* lookup, const int* flag, u16* tableT) {
  __shared__ float tile[64][65];
  int bf = *flag;
  int v0 = blockIdx.x * 64, e0 = blockIdx.y * 64;
  int tx = threadIdx.x, ty = threadIdx.y;  // (64,4)
#pragma unroll
  for (int r = 0; r < 16; ++r) {
    int e = r * 4 + ty, v = tx;
    if (v0 + v < NV)
      tile[e][v] = tanhf(loadIn(lookup, (long)(e0 + e) * NV + v0 + v, bf));
  }
  __syncthreads();
#pragma unroll
  for (int r = 0; r < 16; ++r) {
    int v = r * 4 + ty, e = tx;
    if (v0 + v < NV)
      tableT[(long)(v0 + v) * NE + e0 + e] = f2bf(tile[e][v]);
  }
}

// ---------------- emb (W, B, E) bf16 ----------------
__global__ void embed_kernel(const int* __restrict__ qv,
                             const u16* __restrict__ tableT,
                             u16* __restrict__ emb) {
  int tid = blockIdx.x * 256 + threadIdx.x;
  int token = tid >> 6;   // t*NB + b
  int chunk = tid & 63;   // 8 bf16 each
  int tt = token / NB, b = token % NB;
  int q = qv[b * NW + tt];
  uint4 val = make_uint4(0u, 0u, 0u, 0u);
  if (q > 0) val = *(const uint4*)(tableT + (long)(q - 1) * NE + chunk * 8);
  *(uint4*)(emb + (long)token * NE + chunk * 8) = val;
}

// ---------------- pack weights: Wc[d] rows = [wih | whh], bf16 ----------------
__global__ void pack_kernel(const void* wih0, const void* whh0, const void* b0,
                            const void* wih1, const void* whh1, const void* b1,
                            const int* flag, u16* Wc0, u16* Wc1, float* bsum) {
  const long N0 = 2L * G4 * 1024, N1 = 2L * G4 * 1536;
  long idx = (long)blockIdx.x * 256 + threadIdx.x;
  int bf = *flag;
  if (idx < N0) {
    int d = (int)(idx / (G4 * 1024));
    int rem = (int)(idx % (long)(G4 * 1024));
    int g = rem / 1024, k = rem % 1024;
    float v = (k < 512) ? loadIn(wih0, ((long)d * G4 + g) * 512 + k, bf)
                        : loadIn(whh0, ((long)d * G4 + g) * 512 + (k - 512), bf);
    Wc0[idx] = f2bf(v);
  } else if (idx < N0 + N1) {
    long i2 = idx - N0;
    int d = (int)(i2 / (G4 * 1536));
    int rem = (int)(i2 % (long)(G4 * 1536));
    int g = rem / 1536, k = rem % 1536;
    float v = (k < 1024) ? loadIn(wih1, ((long)d * G4 + g) * 1024 + k, bf)
                         : loadIn(whh1, ((long)d * G4 + g) * 512 + (k - 1024), bf);
    Wc1[i2] = f2bf(v);
  } else if (idx < N0 + N1 + 2L * 2 * G4) {
    long i3 = idx - N0 - N1;  // [layer][d][g]
    int layer = (int)(i3 / (2 * G4));
    int d = (int)((i3 / G4) & 1);
    int g = (int)(i3 % G4);
    const void* bb = layer ? b1 : b0;
    float v = loadIn(bb, (long)d * 2 * G4 + g, bf) +
              loadIn(bb, (long)d * 2 * G4 + G4 + g, bf);
    bsum[i3] = v;
  }
}

// ---------------- zero h (ping 0, both dirs) and c ----------------
__global__ void init_kernel(u16* h0, float* c) {
  int i = blockIdx.x * 256 + threadIdx.x;  // 2*512*512
  h0[i] = 0;
  c[i] = 0.f;
}

// ---------------- fused LSTM step: g = [x;h]@Wc^T + b, cell update ----------
// Block tile: 32 batch rows x 32 hidden units x 4 gates (wave = gate).
// Grid: (16 mtiles, 16 jtiles, 2 dirs). K = Kx + 512, BK = 64.
__global__ __launch_bounds__(256, 2) void lstm_step(
    const u16* __restrict__ xf, const u16* __restrict__ xb, int Kx,
    const u16* __restrict__ hprev, u16* __restrict__ hnext,
    const u16* __restrict__ Wc, const float* __restrict__ bsumL,
    float* __restrict__ cst, u16* __restrict__ h0cat, void* __restrict__ outp,
    const int* __restrict__ qlen, const int* __restrict__ flag, int t,
    int layer) {
  __shared__ __align__(16) char lds[20480];  // [A 4KB][B 16KB]
  const int tid = threadIdx.x;
  const int lane = tid & 63, wv = tid >> 6;
  const int m0 = blockIdx.x * 32, j0 = blockIdx.y * 32, d = blockIdx.z;
  const int K = Kx + 512;
  const u16* xd = d ? xb : xf;
  const u16* hp = hprev + d * (NB * NH);
  const u16* Wd = Wc + (long)d * G4 * K;
  const int col = lane & 15, quad = lane >> 4;

  f32x4 zero = {0.f, 0.f, 0.f, 0.f};
  f32x4 acc[2][2];
#pragma unroll
  for (int i = 0; i < 2; ++i)
#pragma unroll
    for (int j = 0; j < 2; ++j) acc[i][j] = zero;

  const int iters = K >> 6;
  for (int it = 0; it < iters; ++it) {
    int k0 = it << 6;
    // stage A (32x64) + B (4x32x64) via global_load_lds, 5 passes x 4KB
#pragma unroll
    for (int p = 0; p < 5; ++p) {
      int c = p * 256 + tid;
      const u16* gsrc;
      if (c < 256) {  // A tile
        int r = c >> 3, seg = (c & 7) << 3;
        int kk = k0 + (seg ^ ((r & 7) << 3));  // XOR swizzle (bank fix)
        gsrc = (kk < Kx) ? xd + (long)(m0 + r) * Kx + kk
                         : hp + (long)(m0 + r) * NH + (kk - Kx);
      } else {  // B tiles
        int cb = c - 256;
        int g = cb >> 8, j = (cb >> 3) & 31, seg = (cb & 7) << 3;
        int kk = k0 + (seg ^ ((j & 7) << 3));
        gsrc = Wd + (long)(g * 512 + j0 + j) * K + kk;
      }
      __builtin_amdgcn_global_load_lds(
          (__attribute__((address_space(1))) void*)(void*)gsrc,
          (__attribute__((address_space(3))) void*)(lds + p * 4096 + wv * 1024),
          16, 0, 0);
    }
    __syncthreads();
    const u16* As = (const u16*)lds;
    const u16* Bs = (const u16*)(lds + 4096);
#pragma unroll
    for (int ks = 0; ks < 2; ++ks) {
      short8 afr[2], bfr[2];
#pragma unroll
      for (int mf = 0; mf < 2; ++mf) {
        int rm = mf * 16 + col;
        int slot = (ks * 32 + quad * 8) ^ ((rm & 7) << 3);
        afr[mf] = *(const short8*)(As + rm * 64 + slot);
      }
#pragma unroll
      for (int nf = 0; nf < 2; ++nf) {
        int jr = nf * 16 + col;
        int slot = (ks * 32 + quad * 8) ^ ((jr & 7) << 3);
        bfr[nf] = *(const short8*)(Bs + wv * 2048 + jr * 64 + slot);
      }
#pragma unroll
      for (int mf = 0; mf < 2; ++mf)
#pragma unroll
        for (int nf = 0; nf < 2; ++nf)
          acc[mf][nf] = __builtin_amdgcn_mfma_f32_16x16x32_bf16(
              afr[mf], bfr[nf], acc[mf][nf], 0, 0, 0);
    }
    __syncthreads();
  }

  // gate tiles -> LDS fp32 [gate][32][32]
  float* L = (float*)lds;
  float bias[2];
#pragma unroll
  for (int nf = 0; nf < 2; ++nf)
    bias[nf] = bsumL[d * G4 + wv * 512 + j0 + nf * 16 + col];
#pragma unroll
  for (int mf = 0; mf < 2; ++mf)
#pragma unroll
    for (int nf = 0; nf < 2; ++nf)
#pragma unroll
      for (int r = 0; r < 4; ++r) {
        int m = mf * 16 + quad * 4 + r;
        int n = nf * 16 + col;
        L[(wv * 32 + m) * 32 + n] = acc[mf][nf][r] + bias[nf];
      }
  __syncthreads();

  int isbf = *flag;
#pragma unroll
  for (int p = 0; p < 4; ++p) {
    int e = p * 256 + tid;
    int m = e >> 5, n = e & 31;
    float gi = L[(0 * 32 + m) * 32 + n];
    float gf = L[(1 * 32 + m) * 32 + n];
    float gg = L[(2 * 32 + m) * 32 + n];
    float go = L[(3 * 32 + m) * 32 + n];
    int bg = m0 + m, jg = j0 + n;
    float* cp = cst + ((long)d * NB + bg) * NH + jg;
    float cold = *cp;
    float si = 1.f / (1.f + __expf(-gi));
    float sf = 1.f / (1.f + __expf(-gf));
    float so = 1.f / (1.f + __expf(-go));
    float cn = sf * cold + si * tanhf(gg);
    float h = so * tanhf(cn);
    *cp = cn;
    hnext[((long)d * NB + bg) * NH + jg] = f2bf(h);
    int tt = d ? (NW - 1 - t) : t;
    if (layer == 0) {
      h0cat[((long)tt * NB + bg) * (2 * NH) + d * NH + jg] = f2bf(h);
    } else {
      if (qlen[bg] - 1 == tt) {
        long oi = (long)bg * (2 * NH) + d * NH + jg;
        if (isbf)
          ((u16*)outp)[oi] = f2bf(h);
        else
          ((float*)outp)[oi] = h;
      }
    }
  }
}

extern "C" void kernel_launch(void* const* d_in, const int* in_sizes, int n_in,
                              void* d_out, int out_size, void* d_ws,
                              size_t ws_size, hipStream_t stream) {
  const int* qv = (const int*)d_in[0];
  const int* ql = (const int*)d_in[1];
  const void* lookup = d_in[2];
  const void* wih0 = d_in[3];
  const void* whh0 = d_in[4];
  const void* b0 = d_in[5];
  const void* wih1 = d_in[6];
  const void* whh1 = d_in[7];
  const void* b1 = d_in[8];

  char* ws = (char*)d_ws;
  size_t off = 0;
  int* flag = (int*)ws;
  off += 256;
  u16* tableT = (u16*)(ws + off); off += (size_t)NV * NE * 2;          // 12.3 MB
  u16* emb = (u16*)(ws + off);    off += (size_t)NW * NB * NE * 2;     // 21 MB
  u16* h0cat = (u16*)(ws + off);  off += (size_t)NW * NB * 2 * NH * 2; // 42 MB
  u16* Wc0 = (u16*)(ws + off);    off += 2L * G4 * 1024 * 2;           // 8.4 MB
  u16* Wc1 = (u16*)(ws + off);    off += 2L * G4 * 1536 * 2;           // 12.6 MB
  float* bsum = (float*)(ws + off); off += 2L * 2 * G4 * 4;            // 32 KB
  u16* hbuf = (u16*)(ws + off);   off += 2L * 2 * NB * NH * 2;         // 2 MB
  float* cbuf = (float*)(ws + off); off += 2L * NB * NH * 4;           // 2 MB
  // total ~100.4 MB

  detect_kernel<<<1, 64, 0, stream>>>((const u16*)lookup, flag);
  table_kernel<<<dim3(188, 8), dim3(64, 4), 0, stream>>>(lookup, flag, tableT);
  {
    long total = 2L * G4 * 1024 + 2L * G4 * 1536 + 2L * 2 * G4;
    int blocks = (int)((total + 255) / 256);
    pack_kernel<<<blocks, 256, 0, stream>>>(wih0, whh0, b0, wih1, whh1, b1,
                                            flag, Wc0, Wc1, bsum);
  }
  embed_kernel<<<NW * NB / 4, 256, 0, stream>>>(qv, tableT, emb);

  const size_t HB = (size_t)2 * NB * NH;

  // layer 0
  init_kernel<<<2048, 256, 0, stream>>>(hbuf, cbuf);
  for (int t = 0; t < NW; ++t) {
    const u16* hpp = hbuf + (size_t)(t & 1) * HB;
    u16* hnn = hbuf + (size_t)((t + 1) & 1) * HB;
    lstm_step<<<dim3(16, 16, 2), 256, 0, stream>>>(
        emb + (size_t)t * NB * NE, emb + (size_t)(NW - 1 - t) * NB * NE, NE,
        hpp, hnn, Wc0, bsum, cbuf, h0cat, d_out, ql, flag, t, 0);
  }
  // layer 1
  init_kernel<<<2048, 256, 0, stream>>>(hbuf, cbuf);
  for (int t = 0; t < NW; ++t) {
    const u16* hpp = hbuf + (size_t)(t & 1) * HB;
    u16* hnn = hbuf + (size_t)((t + 1) & 1) * HB;
    lstm_step<<<dim3(16, 16, 2), 256, 0, stream>>>(
        h0cat + (size_t)t * NB * 2 * NH,
        h0cat + (size_t)(NW - 1 - t) * NB * 2 * NH, 2 * NH,
        hpp, hnn, Wc1, bsum + 2 * G4, cbuf, h0cat, d_out, ql, flag, t, 1);
  }
}